// Round 15
// baseline (1290.158 us; speedup 1.0000x reference)
//
#include <hip/hip_runtime.h>
#include <hip/hip_fp16.h>

typedef _Float16 half8 __attribute__((ext_vector_type(8)));
typedef float f32x16 __attribute__((ext_vector_type(16)));
typedef float f32x4 __attribute__((ext_vector_type(4)));

#define B_ROWS 16384
#define M_ALL  32768

__device__ __forceinline__ void glds16(void* lds, const void* g) {
  __builtin_amdgcn_global_load_lds(
      (const __attribute__((address_space(1))) unsigned int*)g,
      (__attribute__((address_space(3))) unsigned int*)lds, 16, 0, 0);
}

// ---------------- 128x128 tile GEMM (m97-style, ~877 TF) ----------------
// C[M,N] = A[M,K] @ Bt[N,K]^T.  EPI 1: +bias, ReLU, f16. EPI 2: raw f16.
template<int EPI>
__global__ __launch_bounds__(256, 2)
void gemm128(const _Float16* __restrict__ A, const _Float16* __restrict__ Bt,
             const float* __restrict__ bias, _Float16* __restrict__ Cout,
             int M, int N, int K) {
  __shared__ _Float16 As[128 * 64];
  __shared__ _Float16 Bs[128 * 64];
  const int tid = threadIdx.x;
  const int w = tid >> 6, l = tid & 63;
  const int bm = blockIdx.y << 7, bn = blockIdx.x << 7;
  const int wm = (w >> 1) << 6, wn = (w & 1) << 6;
  const int l31 = l & 31, g5 = l >> 5, l7 = l & 7, l3 = l >> 3;

  f32x16 acc[2][2];
#pragma unroll
  for (int i = 0; i < 2; ++i)
#pragma unroll
    for (int j = 0; j < 2; ++j)
#pragma unroll
      for (int r = 0; r < 16; ++r) acc[i][j][r] = 0.f;

  const int schunk = (l7 ^ l3) * 8;   // LDS[row][p] = G[row][p^(row&7)]
  const int srow = w * 32 + l3;

  for (int kt = 0; kt < K; kt += 64) {
#pragma unroll
    for (int c = 0; c < 4; ++c)
      glds16(&As[w * 2048 + c * 512],
             A + (size_t)(bm + srow + c * 8) * K + kt + schunk);
#pragma unroll
    for (int c = 0; c < 4; ++c)
      glds16(&Bs[w * 2048 + c * 512],
             Bt + (size_t)(bn + srow + c * 8) * K + kt + schunk);
    __syncthreads();
#pragma unroll
    for (int ks = 0; ks < 4; ++ks) {
      const int p0 = (((ks * 2 + g5) ^ l7)) * 8;
      half8 af[2], bf[2];
#pragma unroll
      for (int i = 0; i < 2; ++i)
        af[i] = *(const half8*)&As[(wm + i * 32 + l31) * 64 + p0];
#pragma unroll
      for (int i = 0; i < 2; ++i)
        bf[i] = *(const half8*)&Bs[(wn + i * 32 + l31) * 64 + p0];
#pragma unroll
      for (int i = 0; i < 2; ++i)
#pragma unroll
        for (int j = 0; j < 2; ++j)
          acc[i][j] = __builtin_amdgcn_mfma_f32_32x32x16_f16(af[i], bf[j], acc[i][j], 0, 0, 0);
    }
    __syncthreads();
  }

  // C/D (32x32): col = lane&31, row = (r&3) + 8*(r>>2) + 4*(lane>>5)
#pragma unroll
  for (int i = 0; i < 2; ++i)
#pragma unroll
    for (int j = 0; j < 2; ++j) {
      const int col = bn + wn + j * 32 + l31;
      float bv = 0.f;
      if (EPI == 1) bv = bias[col];
#pragma unroll
      for (int r = 0; r < 16; ++r) {
        const int row = bm + wm + i * 32 + (r & 3) + 8 * (r >> 2) + 4 * g5;
        const float v = acc[i][j][r] + bv;
        Cout[(size_t)row * N + col] = (_Float16)(EPI == 1 ? fmaxf(v, 0.f) : v);
      }
    }
}

// ---- 256x256 tile, 8-wave, reduced-barrier GEMM with hidden A-half1 reads ----
// Requires M%256==0, N%256==0, K%128==0, K>=256. bias+ReLU+f16 epilogue.
// Per K-tile: P0 reads A-half0(aP) + ALL B (b0r,b1r) exposed; after BAR+LGKM0,
// A-half1(aQ) is issued BEFORE MFMA(0,0) -> its 8 ds_reads drain under the
// 32 MFMAs of P0+P1. P1/P3 have no waits. LGKM0 at P2 certifies aQ drained
// before BAR_P3 (WAR certificate for aQ's region staged at P4). Stage slots
// + vmcnt protocol byte-identical to the verified R14 schedule.
#define BAR  __builtin_amdgcn_s_barrier()
#define LGKM0 asm volatile("s_waitcnt lgkmcnt(0)" ::: "memory")
#define VM4  asm volatile("s_waitcnt vmcnt(4)" ::: "memory")
#define VM0  asm volatile("s_waitcnt vmcnt(0)" ::: "memory")
#define LDAH(AS, MH, AR) \
  _Pragma("unroll") for (int mi_ = 0; mi_ < 4; ++mi_) { \
    _Pragma("unroll") for (int t2_ = 0; t2_ < 2; ++t2_) \
      AR[mi_][t2_] = *(const half8*)((AS) + (wm * 128 + ((MH) * 4 + mi_) * 16 + l15) * 64 \
                                        + ((t2_ * 4 + kg) ^ l7) * 8); }
#define LDBH(BS, NH, BR) \
  _Pragma("unroll") for (int nj_ = 0; nj_ < 2; ++nj_) { \
    _Pragma("unroll") for (int t2_ = 0; t2_ < 2; ++t2_) \
      BR[nj_][t2_] = *(const half8*)((BS) + (wn * 64 + ((NH) * 2 + nj_) * 16 + l15) * 64 \
                                        + ((t2_ * 4 + kg) ^ l7) * 8); }
#define MFMA16A(AR, MH, NH, BR) do { \
  __builtin_amdgcn_s_setprio(1); \
  _Pragma("unroll") for (int t2_ = 0; t2_ < 2; ++t2_) \
    _Pragma("unroll") for (int mi_ = 0; mi_ < 4; ++mi_) \
      _Pragma("unroll") for (int nj_ = 0; nj_ < 2; ++nj_) \
        acc[(MH) * 4 + mi_][(NH) * 2 + nj_] = __builtin_amdgcn_mfma_f32_16x16x32_f16( \
            AR[mi_][t2_], BR[nj_][t2_], acc[(MH) * 4 + mi_][(NH) * 2 + nj_], 0, 0, 0); \
  __builtin_amdgcn_s_setprio(0); } while (0)

__global__ __launch_bounds__(512, 2)
void gemm256(const _Float16* __restrict__ A, const _Float16* __restrict__ Bt,
             const float* __restrict__ bias, _Float16* __restrict__ Cout,
             int M, int N, int K) {
  __shared__ _Float16 smem[4 * 256 * 64];  // Abuf0|Abuf1|Bbuf0|Bbuf1 = 128 KiB
  const int tid = threadIdx.x;
  const int w = tid >> 6, l = tid & 63;
  const int nwg = gridDim.x * gridDim.y;
  const int orig = blockIdx.y * gridDim.x + blockIdx.x;
  const int wgid = (orig & 7) * (nwg >> 3) + (orig >> 3);
  const int bx = wgid % gridDim.x, by = wgid / gridDim.x;
  const int bm = by << 8, bn = bx << 8;
  const int wm = w >> 2, wn = w & 3;
  const int l15 = l & 15, kg = l >> 4, l7 = l & 7;

  f32x4 acc[8][4];
#pragma unroll
  for (int i = 0; i < 8; ++i)
#pragma unroll
    for (int j = 0; j < 4; ++j)
#pragma unroll
      for (int r = 0; r < 4; ++r) acc[i][j][r] = 0.f;

  const int srow = tid >> 3;
  const int schunk = ((tid & 7) ^ (srow & 7)) * 8;
  const _Float16* aBase = A + (size_t)(bm + srow) * K + schunk;
  const _Float16* bBase = Bt + (size_t)(bn + srow) * K + schunk;
  const int NT = K >> 6, NI = NT >> 1;

  auto stA = [&](int buf, int h, int t) {
    const _Float16* s = aBase + (size_t)(h * 128) * K + (size_t)t * 64;
    _Float16* d = smem + buf * 16384 + h * 8192 + w * 512;
    glds16(d, s);
    glds16(d + 4096, s + (size_t)64 * K);
  };
  auto stB = [&](int buf, int h, int t) {
    const _Float16* s = bBase + (size_t)(h * 128) * K + (size_t)t * 64;
    _Float16* d = smem + 32768 + buf * 16384 + h * 8192 + w * 512;
    glds16(d, s);
    glds16(d + 4096, s + (size_t)64 * K);
  };

  // prologue: tile0 complete + first 2 halves of tile1; VM4 lands tile0
  stB(0, 0, 0); stA(0, 0, 0); stA(0, 1, 0); stB(0, 1, 0);
  stB(1, 0, 1); stA(1, 0, 1);
  VM4; BAR;

  const _Float16* as0 = smem;
  const _Float16* as1 = smem + 16384;
  const _Float16* bs0 = smem + 32768;
  const _Float16* bs1 = smem + 49152;

  half8 aP[4][2], aQ[4][2], b0r[2][2], b1r[2][2];

  for (int i = 0; i < NI; ++i) {
    const int t1 = 2 * i + 1, tn0 = 2 * i + 2, tn1 = 2 * i + 3;
    const bool s0 = tn0 < NT, s1 = tn1 < NT;
    // ---- K-tile 2i in buf0 ----
    // P0: all exposed reads; aQ issued post-barrier, drains under MFMA
    LDAH(as0, 0, aP); LDBH(bs0, 0, b0r); LDBH(bs0, 1, b1r);
    stA(1, 1, t1);
    BAR; LGKM0;
    LDAH(as0, 1, aQ);
    MFMA16A(aP, 0, 0, b0r);
    // P1
    stB(1, 1, t1);
    BAR;
    MFMA16A(aP, 0, 1, b1r);
    // P2
    if (s0) stB(0, 0, tn0);
    BAR; LGKM0;
    MFMA16A(aQ, 1, 1, b1r);
    // P3
    if (s0) stA(0, 0, tn0);
    BAR;
    MFMA16A(aQ, 1, 0, b0r);
    if (s0) { VM4; } else { VM0; }
    BAR;                                     // handoff: buf1 (tile t1) published
    // ---- K-tile 2i+1 in buf1 ----
    // P4
    LDAH(as1, 0, aP); LDBH(bs1, 0, b0r); LDBH(bs1, 1, b1r);
    if (s0) stA(0, 1, tn0);
    BAR; LGKM0;
    LDAH(as1, 1, aQ);
    MFMA16A(aP, 0, 0, b0r);
    // P5
    if (s0) stB(0, 1, tn0);
    BAR;
    MFMA16A(aP, 0, 1, b1r);
    // P6
    if (s1) stB(1, 0, tn1);
    BAR; LGKM0;
    MFMA16A(aQ, 1, 1, b1r);
    // P7
    if (s1) stA(1, 0, tn1);
    BAR;
    MFMA16A(aQ, 1, 0, b0r);
    if (s1) { VM4; }
    BAR;                                     // handoff: buf0 (tile tn0) published
  }

  // C/D (16x16): col = lane&15, row = (lane>>4)*4 + r  [m89-verified]
#pragma unroll
  for (int nj = 0; nj < 4; ++nj) {
    const int col = bn + wn * 64 + nj * 16 + l15;
    const float bv = bias[col];
#pragma unroll
    for (int mi = 0; mi < 8; ++mi) {
#pragma unroll
      for (int r = 0; r < 4; ++r) {
        const int row = bm + wm * 128 + mi * 16 + (kg << 2) + r;
        Cout[(size_t)row * N + col] = (_Float16)fmaxf(acc[mi][nj][r] + bv, 0.f);
      }
    }
  }
}

// fp32 [Ks,Ns] -> fp16 transposed+padded [Nd,Kd]
__global__ void tpose_pad(const float* __restrict__ src, _Float16* __restrict__ dst,
                          int Ks, int Ns, int Kd, int Nd) {
  __shared__ float t[32][33];
  const int k0 = blockIdx.x * 32, n0 = blockIdx.y * 32;
  const int tx = threadIdx.x & 31, ty = threadIdx.x >> 5;
#pragma unroll
  for (int i = ty; i < 32; i += 8) {
    const int k = k0 + i, n = n0 + tx;
    t[i][tx] = (k < Ks && n < Ns) ? src[(size_t)k * Ns + n] : 0.f;
  }
  __syncthreads();
#pragma unroll
  for (int i = ty; i < 32; i += 8)
    dst[(size_t)(n0 + i) * Kd + (k0 + tx)] = (_Float16)t[tx][i];
}

// stack p/n fp32 [B,C] -> fp16 [2B, Cp] (pad cols zero)
__global__ void cvt_in_k(const float* __restrict__ xp, const float* __restrict__ xn,
                         _Float16* __restrict__ X, int C, int Cp) {
  const size_t total = (size_t)M_ALL * Cp;
  const size_t stride = (size_t)gridDim.x * blockDim.x;
  for (size_t idx = (size_t)blockIdx.x * blockDim.x + threadIdx.x; idx < total; idx += stride) {
    const int r = (int)(idx / Cp);
    const int c = (int)(idx - (size_t)r * Cp);
    float v = 0.f;
    if (c < C) v = (r < B_ROWS) ? xp[(size_t)r * C + c] : xn[(size_t)(r - B_ROWS) * C + c];
    X[idx] = (_Float16)v;
  }
}

// per-column, per-half sum and sumsq of fp16 h[32768, ldh] (cols < C) via atomics
__global__ void stats_k(const _Float16* __restrict__ h, float* __restrict__ sums, int ldh, int C) {
  const int half = blockIdx.y;
  const int nr = B_ROWS / gridDim.x;
  const int r0 = half * B_ROWS + blockIdx.x * nr;
  for (int c = threadIdx.x; c < C; c += blockDim.x) {
    float s = 0.f, q = 0.f;
    for (int r = 0; r < nr; ++r) {
      const float v = (float)h[(size_t)(r0 + r) * ldh + c];
      s += v; q += v * v;
    }
    atomicAdd(&sums[(half * 2 + 0) * 384 + c], s);
    atomicAdd(&sums[(half * 2 + 1) * 384 + c], q);
  }
}

// BN(batch stats, biased var) + ReLU, write fp16 into X1 at column offset coff
__global__ void bn_apply_k(const _Float16* __restrict__ h, const float* __restrict__ sums,
                           const float* __restrict__ gamma, const float* __restrict__ beta,
                           _Float16* __restrict__ X1, int coff) {
  const size_t total = (size_t)M_ALL * 300;
  const size_t stride = (size_t)gridDim.x * blockDim.x;
  for (size_t idx = (size_t)blockIdx.x * blockDim.x + threadIdx.x; idx < total; idx += stride) {
    const int r = (int)(idx / 300);
    const int c = (int)(idx - (size_t)r * 300);
    const int hf = r >> 14;
    const float mean = sums[(hf * 2 + 0) * 384 + c] * (1.f / 16384.f);
    const float ms   = sums[(hf * 2 + 1) * 384 + c] * (1.f / 16384.f);
    const float inv = rsqrtf(ms - mean * mean + 1e-3f) * gamma[c];
    const float y = ((float)h[(size_t)r * 384 + c] - mean) * inv + beta[c];
    X1[(size_t)r * 640 + coff + c] = (_Float16)fmaxf(y, 0.f);
  }
}

// loc branch: h = lat*Wl[0][j] + lon*Wl[1][j]; BN per half; write X1 cols 0..9
__global__ void loc_k(const float* __restrict__ lat_p, const float* __restrict__ lon_p,
                      const float* __restrict__ lat_n, const float* __restrict__ lon_n,
                      const float* __restrict__ Wl, const float* __restrict__ gl,
                      const float* __restrict__ btl, _Float16* __restrict__ X1) {
  const int j = blockIdx.x, half = blockIdx.y;
  const float* lat = half ? lat_n : lat_p;
  const float* lon = half ? lon_n : lon_p;
  const float w0 = Wl[j], w1 = Wl[10 + j];
  const int t = threadIdx.x;
  float s = 0.f, q = 0.f;
  for (int r = t; r < B_ROWS; r += 256) {
    const float v = lat[r] * w0 + lon[r] * w1;
    s += v; q += v * v;
  }
  __shared__ float rs[256], rq[256];
  rs[t] = s; rq[t] = q;
  __syncthreads();
  for (int o = 128; o; o >>= 1) {
    if (t < o) { rs[t] += rs[t + o]; rq[t] += rq[t + o]; }
    __syncthreads();
  }
  const float mean = rs[0] * (1.f / 16384.f);
  const float var = rq[0] * (1.f / 16384.f) - mean * mean;
  const float inv = rsqrtf(var + 1e-3f) * gl[j];
  const float bb = btl[j];
  for (int r = t; r < B_ROWS; r += 256) {
    const float v = lat[r] * w0 + lon[r] * w1;
    const float y = (v - mean) * inv + bb;
    X1[(size_t)(half * B_ROWS + r) * 640 + j] = (_Float16)fmaxf(y, 0.f);
  }
}

// final layer: score[row] = Y[row,:512] . w7 + b7  (one wave per row)
__global__ void scores_k(const _Float16* __restrict__ Y, const float* __restrict__ w7,
                         const float* __restrict__ b7, float* __restrict__ out) {
  const int row = blockIdx.x * 4 + (threadIdx.x >> 6);
  const int l = threadIdx.x & 63;
  const half8 v = *(const half8*)(Y + (size_t)row * 512 + l * 8);
  float s = 0.f;
#pragma unroll
  for (int j = 0; j < 8; ++j) s += (float)v[j] * w7[l * 8 + j];
#pragma unroll
  for (int o = 32; o; o >>= 1) s += __shfl_down(s, o);
  if (l == 0) out[row] = s + b7[0];
}

__global__ void correct_k(const float* __restrict__ sc, const int* __restrict__ mg,
                          float* __restrict__ dst) {
  __shared__ int red[256];
  const int t = threadIdx.x;
  const float m = (float)(*mg);
  int c = 0;
  for (int i = t; i < B_ROWS; i += 256)
    c += (sc[i] - sc[B_ROWS + i]) > m ? 1 : 0;
  red[t] = c;
  __syncthreads();
  for (int o = 128; o; o >>= 1) {
    if (t < o) red[t] += red[t + o];
    __syncthreads();
  }
  if (t == 0) dst[0] = (float)red[0];
}

extern "C" void kernel_launch(void* const* d_in, const int* in_sizes, int n_in,
                              void* d_out, int out_size, void* d_ws, size_t ws_size,
                              hipStream_t stream) {
  const float* img_p = (const float*)d_in[0];
  const float* tag_p = (const float*)d_in[1];
  const float* lat_p = (const float*)d_in[2];
  const float* lon_p = (const float*)d_in[3];
  const float* img_n = (const float*)d_in[4];
  const float* tag_n = (const float*)d_in[5];
  const float* lat_n = (const float*)d_in[6];
  const float* lon_n = (const float*)d_in[7];
  const int*   margin = (const int*)d_in[8];
  const float* Wi = (const float*)d_in[9];
  const float* gi = (const float*)d_in[11];
  const float* bti = (const float*)d_in[12];
  const float* Wt = (const float*)d_in[13];
  const float* gt = (const float*)d_in[15];
  const float* btt = (const float*)d_in[16];
  const float* Wl = (const float*)d_in[17];
  const float* gl = (const float*)d_in[19];
  const float* btl = (const float*)d_in[20];
  const float* W1 = (const float*)d_in[21]; const float* b1 = (const float*)d_in[22];
  const float* W2 = (const float*)d_in[23]; const float* b2 = (const float*)d_in[24];
  const float* W3 = (const float*)d_in[25]; const float* b3 = (const float*)d_in[26];
  const float* W4 = (const float*)d_in[27]; const float* b4 = (const float*)d_in[28];
  const float* W5 = (const float*)d_in[29]; const float* b5 = (const float*)d_in[30];
  const float* W6 = (const float*)d_in[31]; const float* b6 = (const float*)d_in[32];
  const float* W7 = (const float*)d_in[33]; const float* b7 = (const float*)d_in[34];
  float* out = (float*)d_out;

  char* ws = (char*)d_ws;
  size_t off = 0;
  auto alloc = [&](size_t bytes) -> void* {
    void* p = ws + off;
    off += (bytes + 255) & ~(size_t)255;
    return p;
  };
  _Float16* WiT = (_Float16*)alloc((size_t)384 * 320 * 2);
  _Float16* WtT = (_Float16*)alloc((size_t)384 * 320 * 2);
  _Float16* W1T = (_Float16*)alloc((size_t)2048 * 640 * 2);
  _Float16* W2T = (_Float16*)alloc((size_t)2048 * 2048 * 2);
  _Float16* W3T = (_Float16*)alloc((size_t)1024 * 2048 * 2);
  _Float16* W4T = (_Float16*)alloc((size_t)1024 * 1024 * 2);
  _Float16* W5T = (_Float16*)alloc((size_t)512 * 1024 * 2);
  _Float16* W6T = (_Float16*)alloc((size_t)512 * 512 * 2);
  float* sbuf = (float*)alloc((size_t)2 * 4 * 384 * 4);  // [branch][half*2][384]
  _Float16* X1 = (_Float16*)alloc((size_t)M_ALL * 640 * 2);

  const size_t persist = off;
  const size_t avail = ws_size > persist ? ws_size - persist : 0;
  int CR = 4096;
  if (avail >= (size_t)2 * 32768 * 2048 * 2) CR = 32768;
  else if (avail >= (size_t)2 * 16384 * 2048 * 2) CR = 16384;
  else if (avail >= (size_t)2 * 8192 * 2048 * 2) CR = 8192;
  _Float16* Ya = (_Float16*)(ws + persist);
  _Float16* Yb = Ya + (size_t)CR * 2048;
  _Float16* Ximg = Ya;                                     // branch-phase alias
  _Float16* hbuf = (_Float16*)((char*)Ya + (size_t)M_ALL * 320 * 2);

  (void)hipMemsetAsync(X1, 0, (size_t)M_ALL * 640 * 2, stream);
  (void)hipMemsetAsync(sbuf, 0, (size_t)2 * 4 * 384 * 4, stream);

  tpose_pad<<<dim3(10, 12), 256, 0, stream>>>(Wi, WiT, 300, 300, 320, 384);
  tpose_pad<<<dim3(10, 12), 256, 0, stream>>>(Wt, WtT, 300, 300, 320, 384);
  tpose_pad<<<dim3(20, 64), 256, 0, stream>>>(W1, W1T, 610, 2048, 640, 2048);
  tpose_pad<<<dim3(64, 64), 256, 0, stream>>>(W2, W2T, 2048, 2048, 2048, 2048);
  tpose_pad<<<dim3(64, 32), 256, 0, stream>>>(W3, W3T, 2048, 1024, 2048, 1024);
  tpose_pad<<<dim3(32, 32), 256, 0, stream>>>(W4, W4T, 1024, 1024, 1024, 1024);
  tpose_pad<<<dim3(32, 16), 256, 0, stream>>>(W5, W5T, 1024, 512, 1024, 512);
  tpose_pad<<<dim3(16, 16), 256, 0, stream>>>(W6, W6T, 512, 512, 512, 512);

  // img branch
  cvt_in_k<<<2048, 256, 0, stream>>>(img_p, img_n, Ximg, 300, 320);
  gemm128<2><<<dim3(3, 256), 256, 0, stream>>>(Ximg, WiT, nullptr, hbuf, M_ALL, 384, 320);
  stats_k<<<dim3(128, 2), 256, 0, stream>>>(hbuf, sbuf, 384, 300);
  bn_apply_k<<<2048, 256, 0, stream>>>(hbuf, sbuf, gi, bti, X1, 10);
  // tag branch
  cvt_in_k<<<2048, 256, 0, stream>>>(tag_p, tag_n, Ximg, 300, 320);
  gemm128<2><<<dim3(3, 256), 256, 0, stream>>>(Ximg, WtT, nullptr, hbuf, M_ALL, 384, 320);
  stats_k<<<dim3(128, 2), 256, 0, stream>>>(hbuf, sbuf + 4 * 384, 384, 300);
  bn_apply_k<<<2048, 256, 0, stream>>>(hbuf, sbuf + 4 * 384, gt, btt, X1, 310);
  // loc branch
  loc_k<<<dim3(10, 2), 256, 0, stream>>>(lat_p, lon_p, lat_n, lon_n, Wl, gl, btl, X1);

  // main stack, chunked over M. L1-L4 (N>=1024): 256^2 pipelined kernel;
  // L5/L6 (N=512): 128^2 kernel.
  for (int c0 = 0; c0 < M_ALL; c0 += CR) {
    const int rb = CR / 128, rb2 = CR / 256;
    const _Float16* Xc = X1 + (size_t)c0 * 640;
    gemm256<<<dim3(8, rb2), 512, 0, stream>>>(Xc, W1T, b1, Ya, CR, 2048, 640);
    gemm256<<<dim3(8, rb2), 512, 0, stream>>>(Ya, W2T, b2, Yb, CR, 2048, 2048);
    gemm256<<<dim3(4, rb2), 512, 0, stream>>>(Yb, W3T, b3, Ya, CR, 1024, 2048);
    gemm256<<<dim3(4, rb2), 512, 0, stream>>>(Ya, W4T, b4, Yb, CR, 1024, 1024);
    gemm128<1><<<dim3(4, rb), 256, 0, stream>>>(Yb, W5T, b5, Ya, CR, 512, 1024);
    gemm128<1><<<dim3(4, rb), 256, 0, stream>>>(Ya, W6T, b6, Yb, CR, 512, 512);
    scores_k<<<CR / 4, 256, 0, stream>>>(Yb, W7, b7, out + c0);
  }

  correct_k<<<1, 256, 0, stream>>>(out, margin, out + 32768);
}

// Round 16
// 906.934 us; speedup vs baseline: 1.4225x; 1.4225x over previous
//
#include <hip/hip_runtime.h>
#include <hip/hip_fp16.h>

typedef _Float16 half8 __attribute__((ext_vector_type(8)));
typedef float f32x16 __attribute__((ext_vector_type(16)));
typedef float f32x4 __attribute__((ext_vector_type(4)));

#define B_ROWS 16384
#define M_ALL  32768

__device__ __forceinline__ void glds16(void* lds, const void* g) {
  __builtin_amdgcn_global_load_lds(
      (const __attribute__((address_space(1))) unsigned int*)g,
      (__attribute__((address_space(3))) unsigned int*)lds, 16, 0, 0);
}

// ---------------- 128x128 tile GEMM (m97-style, ~877 TF) ----------------
// C[M,N] = A[M,K] @ Bt[N,K]^T.  EPI 1: +bias, ReLU, f16. EPI 2: raw f16.
template<int EPI>
__global__ __launch_bounds__(256, 2)
void gemm128(const _Float16* __restrict__ A, const _Float16* __restrict__ Bt,
             const float* __restrict__ bias, _Float16* __restrict__ Cout,
             int M, int N, int K) {
  __shared__ _Float16 As[128 * 64];
  __shared__ _Float16 Bs[128 * 64];
  const int tid = threadIdx.x;
  const int w = tid >> 6, l = tid & 63;
  const int bm = blockIdx.y << 7, bn = blockIdx.x << 7;
  const int wm = (w >> 1) << 6, wn = (w & 1) << 6;
  const int l31 = l & 31, g5 = l >> 5, l7 = l & 7, l3 = l >> 3;

  f32x16 acc[2][2];
#pragma unroll
  for (int i = 0; i < 2; ++i)
#pragma unroll
    for (int j = 0; j < 2; ++j)
#pragma unroll
      for (int r = 0; r < 16; ++r) acc[i][j][r] = 0.f;

  const int schunk = (l7 ^ l3) * 8;   // LDS[row][p] = G[row][p^(row&7)]
  const int srow = w * 32 + l3;

  for (int kt = 0; kt < K; kt += 64) {
#pragma unroll
    for (int c = 0; c < 4; ++c)
      glds16(&As[w * 2048 + c * 512],
             A + (size_t)(bm + srow + c * 8) * K + kt + schunk);
#pragma unroll
    for (int c = 0; c < 4; ++c)
      glds16(&Bs[w * 2048 + c * 512],
             Bt + (size_t)(bn + srow + c * 8) * K + kt + schunk);
    __syncthreads();
#pragma unroll
    for (int ks = 0; ks < 4; ++ks) {
      const int p0 = (((ks * 2 + g5) ^ l7)) * 8;
      half8 af[2], bf[2];
#pragma unroll
      for (int i = 0; i < 2; ++i)
        af[i] = *(const half8*)&As[(wm + i * 32 + l31) * 64 + p0];
#pragma unroll
      for (int i = 0; i < 2; ++i)
        bf[i] = *(const half8*)&Bs[(wn + i * 32 + l31) * 64 + p0];
#pragma unroll
      for (int i = 0; i < 2; ++i)
#pragma unroll
        for (int j = 0; j < 2; ++j)
          acc[i][j] = __builtin_amdgcn_mfma_f32_32x32x16_f16(af[i], bf[j], acc[i][j], 0, 0, 0);
    }
    __syncthreads();
  }

  // C/D (32x32): col = lane&31, row = (r&3) + 8*(r>>2) + 4*(lane>>5)
#pragma unroll
  for (int i = 0; i < 2; ++i)
#pragma unroll
    for (int j = 0; j < 2; ++j) {
      const int col = bn + wn + j * 32 + l31;
      float bv = 0.f;
      if (EPI == 1) bv = bias[col];
#pragma unroll
      for (int r = 0; r < 16; ++r) {
        const int row = bm + wm + i * 32 + (r & 3) + 8 * (r >> 2) + 4 * g5;
        const float v = acc[i][j][r] + bv;
        Cout[(size_t)row * N + col] = (_Float16)(EPI == 1 ? fmaxf(v, 0.f) : v);
      }
    }
}

// -- 256x256 tile, 8-wave GEMM: R14 schedule + deferred-Q10 handoff coverage --
// Requires M%256==0, N%256==0, K%128==0, K>=256. bias+ReLU+f16 epilogue.
// R14's reduced-barrier schedule, with each tile's last MFMA (Q10 — operands
// aQ/b0r already in regs) moved AFTER the handoff VM+BAR. Post-handoff reads
// then drain under slow waves' deferred MFMA (the one fully-exposed read
// window in R14). 4 barriers/tile. Stage slots + vmcnt accounting identical
// to R14 (verified: 12-load in-flight walk unchanged). Max frag liveness 64
// regs (no spill; R11/R15 showed +32 spills).
#define BAR  __builtin_amdgcn_s_barrier()
#define SCB0 __builtin_amdgcn_sched_barrier(0)
#define LGKM0 asm volatile("s_waitcnt lgkmcnt(0)" ::: "memory")
#define LGKM8 asm volatile("s_waitcnt lgkmcnt(8)" ::: "memory")
#define VM4  asm volatile("s_waitcnt vmcnt(4)" ::: "memory")
#define VM0  asm volatile("s_waitcnt vmcnt(0)" ::: "memory")
#define LDAH(AS, MH, AR) \
  _Pragma("unroll") for (int mi_ = 0; mi_ < 4; ++mi_) { \
    _Pragma("unroll") for (int t2_ = 0; t2_ < 2; ++t2_) \
      AR[mi_][t2_] = *(const half8*)((AS) + (wm * 128 + ((MH) * 4 + mi_) * 16 + l15) * 64 \
                                        + ((t2_ * 4 + kg) ^ l7) * 8); }
#define LDBH(BS, NH, BR) \
  _Pragma("unroll") for (int nj_ = 0; nj_ < 2; ++nj_) { \
    _Pragma("unroll") for (int t2_ = 0; t2_ < 2; ++t2_) \
      BR[nj_][t2_] = *(const half8*)((BS) + (wn * 64 + ((NH) * 2 + nj_) * 16 + l15) * 64 \
                                        + ((t2_ * 4 + kg) ^ l7) * 8); }
#define MFMA16A(AR, MH, NH, BR) do { \
  __builtin_amdgcn_s_setprio(1); \
  _Pragma("unroll") for (int t2_ = 0; t2_ < 2; ++t2_) \
    _Pragma("unroll") for (int mi_ = 0; mi_ < 4; ++mi_) \
      _Pragma("unroll") for (int nj_ = 0; nj_ < 2; ++nj_) \
        acc[(MH) * 4 + mi_][(NH) * 2 + nj_] = __builtin_amdgcn_mfma_f32_16x16x32_f16( \
            AR[mi_][t2_], BR[nj_][t2_], acc[(MH) * 4 + mi_][(NH) * 2 + nj_], 0, 0, 0); \
  __builtin_amdgcn_s_setprio(0); } while (0)

__global__ __launch_bounds__(512, 2)
void gemm256(const _Float16* __restrict__ A, const _Float16* __restrict__ Bt,
             const float* __restrict__ bias, _Float16* __restrict__ Cout,
             int M, int N, int K) {
  __shared__ _Float16 smem[4 * 256 * 64];  // Abuf0|Abuf1|Bbuf0|Bbuf1 = 128 KiB
  const int tid = threadIdx.x;
  const int w = tid >> 6, l = tid & 63;
  const int nwg = gridDim.x * gridDim.y;
  const int orig = blockIdx.y * gridDim.x + blockIdx.x;
  const int wgid = (orig & 7) * (nwg >> 3) + (orig >> 3);
  const int bx = wgid % gridDim.x, by = wgid / gridDim.x;
  const int bm = by << 8, bn = bx << 8;
  const int wm = w >> 2, wn = w & 3;
  const int l15 = l & 15, kg = l >> 4, l7 = l & 7;

  f32x4 acc[8][4];
#pragma unroll
  for (int i = 0; i < 8; ++i)
#pragma unroll
    for (int j = 0; j < 4; ++j)
#pragma unroll
      for (int r = 0; r < 4; ++r) acc[i][j][r] = 0.f;

  const int srow = tid >> 3;
  const int schunk = ((tid & 7) ^ (srow & 7)) * 8;
  const _Float16* aBase = A + (size_t)(bm + srow) * K + schunk;
  const _Float16* bBase = Bt + (size_t)(bn + srow) * K + schunk;
  const int NT = K >> 6, NI = NT >> 1;

  auto stA = [&](int buf, int h, int t) {
    const _Float16* s = aBase + (size_t)(h * 128) * K + (size_t)t * 64;
    _Float16* d = smem + buf * 16384 + h * 8192 + w * 512;
    glds16(d, s);
    glds16(d + 4096, s + (size_t)64 * K);
  };
  auto stB = [&](int buf, int h, int t) {
    const _Float16* s = bBase + (size_t)(h * 128) * K + (size_t)t * 64;
    _Float16* d = smem + 32768 + buf * 16384 + h * 8192 + w * 512;
    glds16(d, s);
    glds16(d + 4096, s + (size_t)64 * K);
  };

  // prologue: tile0 complete + first 2 halves of tile1; VM4 lands tile0
  stB(0, 0, 0); stA(0, 0, 0); stA(0, 1, 0); stB(0, 1, 0);
  stB(1, 0, 1); stA(1, 0, 1);
  VM4; BAR;

  const _Float16* as0 = smem;
  const _Float16* as1 = smem + 16384;
  const _Float16* bs0 = smem + 32768;
  const _Float16* bs1 = smem + 49152;

  half8 aP[4][2], aQ[4][2], b0r[2][2], b1r[2][2];

  for (int i = 0; i < NI; ++i) {
    const int t1 = 2 * i + 1, tn0 = 2 * i + 2, tn1 = 2 * i + 3;
    const bool s0 = tn0 < NT, s1 = tn1 < NT;
    // ---- K-tile 2i in buf0 ----
    // P0
    LDAH(as0, 0, aP); LDBH(bs0, 0, b0r);
    stA(1, 1, t1);
    LGKM8; BAR; LGKM0; MFMA16A(aP, 0, 0, b0r);
    // P1
    LDBH(bs0, 1, b1r);
    stB(1, 1, t1);
    BAR; LGKM0; MFMA16A(aP, 0, 1, b1r);
    // P2
    LDAH(as0, 1, aQ);
    if (s0) stB(0, 0, tn0);
    BAR; LGKM0; MFMA16A(aQ, 1, 1, b1r);
    // P3: stage, handoff, DEFERRED Q10 (covers next phase's reads)
    if (s0) stA(0, 0, tn0);
    if (s0) { VM4; } else { VM0; }
    BAR; SCB0;                               // handoff: buf1 (tile t1) published
    MFMA16A(aQ, 1, 0, b0r);
    // ---- K-tile 2i+1 in buf1 ----
    // P4
    LDAH(as1, 0, aP); LDBH(bs1, 0, b0r);
    if (s0) stA(0, 1, tn0);
    LGKM8; BAR; LGKM0; MFMA16A(aP, 0, 0, b0r);
    // P5
    LDBH(bs1, 1, b1r);
    if (s0) stB(0, 1, tn0);
    BAR; LGKM0; MFMA16A(aP, 0, 1, b1r);
    // P6
    LDAH(as1, 1, aQ);
    if (s1) stB(1, 0, tn1);
    BAR; LGKM0; MFMA16A(aQ, 1, 1, b1r);
    // P7: stage, handoff, DEFERRED Q10
    if (s1) stA(1, 0, tn1);
    if (s1) { VM4; }
    BAR; SCB0;                               // handoff: buf0 (tile tn0) published
    MFMA16A(aQ, 1, 0, b0r);
  }

  // C/D (16x16): col = lane&15, row = (lane>>4)*4 + r  [m89-verified]
#pragma unroll
  for (int nj = 0; nj < 4; ++nj) {
    const int col = bn + wn * 64 + nj * 16 + l15;
    const float bv = bias[col];
#pragma unroll
    for (int mi = 0; mi < 8; ++mi) {
#pragma unroll
      for (int r = 0; r < 4; ++r) {
        const int row = bm + wm * 128 + mi * 16 + (kg << 2) + r;
        Cout[(size_t)row * N + col] = (_Float16)fmaxf(acc[mi][nj][r] + bv, 0.f);
      }
    }
  }
}

// fp32 [Ks,Ns] -> fp16 transposed+padded [Nd,Kd]
__global__ void tpose_pad(const float* __restrict__ src, _Float16* __restrict__ dst,
                          int Ks, int Ns, int Kd, int Nd) {
  __shared__ float t[32][33];
  const int k0 = blockIdx.x * 32, n0 = blockIdx.y * 32;
  const int tx = threadIdx.x & 31, ty = threadIdx.x >> 5;
#pragma unroll
  for (int i = ty; i < 32; i += 8) {
    const int k = k0 + i, n = n0 + tx;
    t[i][tx] = (k < Ks && n < Ns) ? src[(size_t)k * Ns + n] : 0.f;
  }
  __syncthreads();
#pragma unroll
  for (int i = ty; i < 32; i += 8)
    dst[(size_t)(n0 + i) * Kd + (k0 + tx)] = (_Float16)t[tx][i];
}

// stack p/n fp32 [B,C] -> fp16 [2B, Cp] (pad cols zero)
__global__ void cvt_in_k(const float* __restrict__ xp, const float* __restrict__ xn,
                         _Float16* __restrict__ X, int C, int Cp) {
  const size_t total = (size_t)M_ALL * Cp;
  const size_t stride = (size_t)gridDim.x * blockDim.x;
  for (size_t idx = (size_t)blockIdx.x * blockDim.x + threadIdx.x; idx < total; idx += stride) {
    const int r = (int)(idx / Cp);
    const int c = (int)(idx - (size_t)r * Cp);
    float v = 0.f;
    if (c < C) v = (r < B_ROWS) ? xp[(size_t)r * C + c] : xn[(size_t)(r - B_ROWS) * C + c];
    X[idx] = (_Float16)v;
  }
}

// per-column, per-half sum and sumsq of fp16 h[32768, ldh] (cols < C) via atomics
__global__ void stats_k(const _Float16* __restrict__ h, float* __restrict__ sums, int ldh, int C) {
  const int half = blockIdx.y;
  const int nr = B_ROWS / gridDim.x;
  const int r0 = half * B_ROWS + blockIdx.x * nr;
  for (int c = threadIdx.x; c < C; c += blockDim.x) {
    float s = 0.f, q = 0.f;
    for (int r = 0; r < nr; ++r) {
      const float v = (float)h[(size_t)(r0 + r) * ldh + c];
      s += v; q += v * v;
    }
    atomicAdd(&sums[(half * 2 + 0) * 384 + c], s);
    atomicAdd(&sums[(half * 2 + 1) * 384 + c], q);
  }
}

// BN(batch stats, biased var) + ReLU, write fp16 into X1 at column offset coff
__global__ void bn_apply_k(const _Float16* __restrict__ h, const float* __restrict__ sums,
                           const float* __restrict__ gamma, const float* __restrict__ beta,
                           _Float16* __restrict__ X1, int coff) {
  const size_t total = (size_t)M_ALL * 300;
  const size_t stride = (size_t)gridDim.x * blockDim.x;
  for (size_t idx = (size_t)blockIdx.x * blockDim.x + threadIdx.x; idx < total; idx += stride) {
    const int r = (int)(idx / 300);
    const int c = (int)(idx - (size_t)r * 300);
    const int hf = r >> 14;
    const float mean = sums[(hf * 2 + 0) * 384 + c] * (1.f / 16384.f);
    const float ms   = sums[(hf * 2 + 1) * 384 + c] * (1.f / 16384.f);
    const float inv = rsqrtf(ms - mean * mean + 1e-3f) * gamma[c];
    const float y = ((float)h[(size_t)r * 384 + c] - mean) * inv + beta[c];
    X1[(size_t)r * 640 + coff + c] = (_Float16)fmaxf(y, 0.f);
  }
}

// loc branch: h = lat*Wl[0][j] + lon*Wl[1][j]; BN per half; write X1 cols 0..9
__global__ void loc_k(const float* __restrict__ lat_p, const float* __restrict__ lon_p,
                      const float* __restrict__ lat_n, const float* __restrict__ lon_n,
                      const float* __restrict__ Wl, const float* __restrict__ gl,
                      const float* __restrict__ btl, _Float16* __restrict__ X1) {
  const int j = blockIdx.x, half = blockIdx.y;
  const float* lat = half ? lat_n : lat_p;
  const float* lon = half ? lon_n : lon_p;
  const float w0 = Wl[j], w1 = Wl[10 + j];
  const int t = threadIdx.x;
  float s = 0.f, q = 0.f;
  for (int r = t; r < B_ROWS; r += 256) {
    const float v = lat[r] * w0 + lon[r] * w1;
    s += v; q += v * v;
  }
  __shared__ float rs[256], rq[256];
  rs[t] = s; rq[t] = q;
  __syncthreads();
  for (int o = 128; o; o >>= 1) {
    if (t < o) { rs[t] += rs[t + o]; rq[t] += rq[t + o]; }
    __syncthreads();
  }
  const float mean = rs[0] * (1.f / 16384.f);
  const float var = rq[0] * (1.f / 16384.f) - mean * mean;
  const float inv = rsqrtf(var + 1e-3f) * gl[j];
  const float bb = btl[j];
  for (int r = t; r < B_ROWS; r += 256) {
    const float v = lat[r] * w0 + lon[r] * w1;
    const float y = (v - mean) * inv + bb;
    X1[(size_t)(half * B_ROWS + r) * 640 + j] = (_Float16)fmaxf(y, 0.f);
  }
}

// final layer: score[row] = Y[row,:512] . w7 + b7  (one wave per row)
__global__ void scores_k(const _Float16* __restrict__ Y, const float* __restrict__ w7,
                         const float* __restrict__ b7, float* __restrict__ out) {
  const int row = blockIdx.x * 4 + (threadIdx.x >> 6);
  const int l = threadIdx.x & 63;
  const half8 v = *(const half8*)(Y + (size_t)row * 512 + l * 8);
  float s = 0.f;
#pragma unroll
  for (int j = 0; j < 8; ++j) s += (float)v[j] * w7[l * 8 + j];
#pragma unroll
  for (int o = 32; o; o >>= 1) s += __shfl_down(s, o);
  if (l == 0) out[row] = s + b7[0];
}

__global__ void correct_k(const float* __restrict__ sc, const int* __restrict__ mg,
                          float* __restrict__ dst) {
  __shared__ int red[256];
  const int t = threadIdx.x;
  const float m = (float)(*mg);
  int c = 0;
  for (int i = t; i < B_ROWS; i += 256)
    c += (sc[i] - sc[B_ROWS + i]) > m ? 1 : 0;
  red[t] = c;
  __syncthreads();
  for (int o = 128; o; o >>= 1) {
    if (t < o) red[t] += red[t + o];
    __syncthreads();
  }
  if (t == 0) dst[0] = (float)red[0];
}

extern "C" void kernel_launch(void* const* d_in, const int* in_sizes, int n_in,
                              void* d_out, int out_size, void* d_ws, size_t ws_size,
                              hipStream_t stream) {
  const float* img_p = (const float*)d_in[0];
  const float* tag_p = (const float*)d_in[1];
  const float* lat_p = (const float*)d_in[2];
  const float* lon_p = (const float*)d_in[3];
  const float* img_n = (const float*)d_in[4];
  const float* tag_n = (const float*)d_in[5];
  const float* lat_n = (const float*)d_in[6];
  const float* lon_n = (const float*)d_in[7];
  const int*   margin = (const int*)d_in[8];
  const float* Wi = (const float*)d_in[9];
  const float* gi = (const float*)d_in[11];
  const float* bti = (const float*)d_in[12];
  const float* Wt = (const float*)d_in[13];
  const float* gt = (const float*)d_in[15];
  const float* btt = (const float*)d_in[16];
  const float* Wl = (const float*)d_in[17];
  const float* gl = (const float*)d_in[19];
  const float* btl = (const float*)d_in[20];
  const float* W1 = (const float*)d_in[21]; const float* b1 = (const float*)d_in[22];
  const float* W2 = (const float*)d_in[23]; const float* b2 = (const float*)d_in[24];
  const float* W3 = (const float*)d_in[25]; const float* b3 = (const float*)d_in[26];
  const float* W4 = (const float*)d_in[27]; const float* b4 = (const float*)d_in[28];
  const float* W5 = (const float*)d_in[29]; const float* b5 = (const float*)d_in[30];
  const float* W6 = (const float*)d_in[31]; const float* b6 = (const float*)d_in[32];
  const float* W7 = (const float*)d_in[33]; const float* b7 = (const float*)d_in[34];
  float* out = (float*)d_out;

  char* ws = (char*)d_ws;
  size_t off = 0;
  auto alloc = [&](size_t bytes) -> void* {
    void* p = ws + off;
    off += (bytes + 255) & ~(size_t)255;
    return p;
  };
  _Float16* WiT = (_Float16*)alloc((size_t)384 * 320 * 2);
  _Float16* WtT = (_Float16*)alloc((size_t)384 * 320 * 2);
  _Float16* W1T = (_Float16*)alloc((size_t)2048 * 640 * 2);
  _Float16* W2T = (_Float16*)alloc((size_t)2048 * 2048 * 2);
  _Float16* W3T = (_Float16*)alloc((size_t)1024 * 2048 * 2);
  _Float16* W4T = (_Float16*)alloc((size_t)1024 * 1024 * 2);
  _Float16* W5T = (_Float16*)alloc((size_t)512 * 1024 * 2);
  _Float16* W6T = (_Float16*)alloc((size_t)512 * 512 * 2);
  float* sbuf = (float*)alloc((size_t)2 * 4 * 384 * 4);  // [branch][half*2][384]
  _Float16* X1 = (_Float16*)alloc((size_t)M_ALL * 640 * 2);

  const size_t persist = off;
  const size_t avail = ws_size > persist ? ws_size - persist : 0;
  int CR = 4096;
  if (avail >= (size_t)2 * 32768 * 2048 * 2) CR = 32768;
  else if (avail >= (size_t)2 * 16384 * 2048 * 2) CR = 16384;
  else if (avail >= (size_t)2 * 8192 * 2048 * 2) CR = 8192;
  _Float16* Ya = (_Float16*)(ws + persist);
  _Float16* Yb = Ya + (size_t)CR * 2048;
  _Float16* Ximg = Ya;                                     // branch-phase alias
  _Float16* hbuf = (_Float16*)((char*)Ya + (size_t)M_ALL * 320 * 2);

  (void)hipMemsetAsync(X1, 0, (size_t)M_ALL * 640 * 2, stream);
  (void)hipMemsetAsync(sbuf, 0, (size_t)2 * 4 * 384 * 4, stream);

  tpose_pad<<<dim3(10, 12), 256, 0, stream>>>(Wi, WiT, 300, 300, 320, 384);
  tpose_pad<<<dim3(10, 12), 256, 0, stream>>>(Wt, WtT, 300, 300, 320, 384);
  tpose_pad<<<dim3(20, 64), 256, 0, stream>>>(W1, W1T, 610, 2048, 640, 2048);
  tpose_pad<<<dim3(64, 64), 256, 0, stream>>>(W2, W2T, 2048, 2048, 2048, 2048);
  tpose_pad<<<dim3(64, 32), 256, 0, stream>>>(W3, W3T, 2048, 1024, 2048, 1024);
  tpose_pad<<<dim3(32, 32), 256, 0, stream>>>(W4, W4T, 1024, 1024, 1024, 1024);
  tpose_pad<<<dim3(32, 16), 256, 0, stream>>>(W5, W5T, 1024, 512, 1024, 512);
  tpose_pad<<<dim3(16, 16), 256, 0, stream>>>(W6, W6T, 512, 512, 512, 512);

  // img branch
  cvt_in_k<<<2048, 256, 0, stream>>>(img_p, img_n, Ximg, 300, 320);
  gemm128<2><<<dim3(3, 256), 256, 0, stream>>>(Ximg, WiT, nullptr, hbuf, M_ALL, 384, 320);
  stats_k<<<dim3(128, 2), 256, 0, stream>>>(hbuf, sbuf, 384, 300);
  bn_apply_k<<<2048, 256, 0, stream>>>(hbuf, sbuf, gi, bti, X1, 10);
  // tag branch
  cvt_in_k<<<2048, 256, 0, stream>>>(tag_p, tag_n, Ximg, 300, 320);
  gemm128<2><<<dim3(3, 256), 256, 0, stream>>>(Ximg, WtT, nullptr, hbuf, M_ALL, 384, 320);
  stats_k<<<dim3(128, 2), 256, 0, stream>>>(hbuf, sbuf + 4 * 384, 384, 300);
  bn_apply_k<<<2048, 256, 0, stream>>>(hbuf, sbuf + 4 * 384, gt, btt, X1, 310);
  // loc branch
  loc_k<<<dim3(10, 2), 256, 0, stream>>>(lat_p, lon_p, lat_n, lon_n, Wl, gl, btl, X1);

  // main stack, chunked over M. L1-L4 (N>=1024): 256^2 pipelined kernel;
  // L5/L6 (N=512): 128^2 kernel.
  for (int c0 = 0; c0 < M_ALL; c0 += CR) {
    const int rb = CR / 128, rb2 = CR / 256;
    const _Float16* Xc = X1 + (size_t)c0 * 640;
    gemm256<<<dim3(8, rb2), 512, 0, stream>>>(Xc, W1T, b1, Ya, CR, 2048, 640);
    gemm256<<<dim3(8, rb2), 512, 0, stream>>>(Ya, W2T, b2, Yb, CR, 2048, 2048);
    gemm256<<<dim3(4, rb2), 512, 0, stream>>>(Yb, W3T, b3, Ya, CR, 1024, 2048);
    gemm256<<<dim3(4, rb2), 512, 0, stream>>>(Ya, W4T, b4, Yb, CR, 1024, 1024);
    gemm128<1><<<dim3(4, rb), 256, 0, stream>>>(Yb, W5T, b5, Ya, CR, 512, 1024);
    gemm128<1><<<dim3(4, rb), 256, 0, stream>>>(Ya, W6T, b6, Yb, CR, 512, 512);
    scores_k<<<CR / 4, 256, 0, stream>>>(Yb, W7, b7, out + c0);
  }

  correct_k<<<1, 256, 0, stream>>>(out, margin, out + 32768);
}